// Round 2
// baseline (182.059 us; speedup 1.0000x reference)
//
#include <hip/hip_runtime.h>
#include <math.h>

#define N_  32
#define T_  8192
#define D_  64
#define K_  64
#define CHUNKS 32
#define TOK_PER_BLOCK (T_ / CHUNKS)    // 256
#define TB 64                          // tokens per batch
#define NBATCH (TOK_PER_BLOCK / TB)    // 4
#define STATS_PER_N (K_ + 2 * K_ * D_) // 8256

typedef _Float16 half_t;
typedef __attribute__((ext_vector_type(8)))  _Float16 v8h;
typedef __attribute__((ext_vector_type(4)))  float    v4f;
typedef __attribute__((ext_vector_type(16))) float    v16f;

// async global->LDS DMA, 16B per lane, LDS dest = uniform base + lane*16
__device__ __forceinline__ void gll16(const void* g, void* l) {
    __builtin_amdgcn_global_load_lds((const unsigned int*)g, (unsigned int*)l, 16, 0, 0);
}

// ---------------------------------------------------------------------------
// prep (grid 9): blocks 0..7 pack WH (f16 MFMA A-frag order);
// block 8: Ap[k] = 2 log w - 0.5*sum_d(log c + mu^2/c), and zero ssq[32].
// ---------------------------------------------------------------------------
__global__ void prep_kernel(const float* __restrict__ w, const float* __restrict__ mu,
                            const float* __restrict__ cv, float* __restrict__ Ap,
                            half_t* __restrict__ WH, float* __restrict__ ssq) {
    if (blockIdx.x < 8) {
#pragma unroll
        for (int i = 0; i < 4; ++i) {
            const int e = blockIdx.x * 1024 + i * 256 + threadIdx.x;  // 0..8191
            const int j = e & 7, l = (e >> 3) & 63, fs = e >> 9;
            const int tile = fs >> 2, s = fs & 3;
            const int kc = 16 * tile + (l & 15);
            const int f  = 32 * s + 8 * (l >> 4) + j;
            float val;
            if (f < 64) val = mu[kc * 64 + f] / cv[kc * 64 + f];
            else        val = -0.5f / cv[kc * 64 + (f - 64)];
            WH[e] = (half_t)val;
        }
    } else {
        if (threadIdx.x < 32) ssq[threadIdx.x] = 0.f;
        if (threadIdx.x < K_) {
            const int k = threadIdx.x;
            float acc = 0.f;
            for (int d = 0; d < D_; ++d) {
                const int idx = k * D_ + d;
                const float c = cv[idx], m = mu[idx];
                acc += logf(c) + m * m / c;
            }
            Ap[k] = 2.f * logf(w[k]) - 0.5f * acc;
        }
    }
}

// ---------------------------------------------------------------------------
// main: grid (32, 32) = 1024 blocks, block 256 (4 waves), 4 blocks/CU.
// R2 redesign:
//  - x staged per batch via global_load_lds into Xf (f32, 16KB, single buffer).
//    DMA source is pre-swizzled per lane (chunk ^= row&15) so the linear LDS
//    dest holds a swizzled layout -> conflict-free reads in both phases.
//  - WH lives in LDS (16KB, copied once per block by DMA): zero per-batch
//    HBM/L2 traffic for weights (R1's WH global stream cost +82MB HBM fetch).
//  - Pt[64][64] f16 with 8-col-block XOR swizzle (no pad). LDS total =
//    16384+16384+8192 = 40960 B exactly -> 4 blocks/CU (160KB).
//  - Ap bias in 4 v4f registers; s0sh reuses Pt storage at flush.
//  - partials stores nontemporal (don't flood L2).
// Phase A reads ONLY its own wave's x rows -> own vmcnt(0) suffices, no
// barrier before A. Post-A barrier guarantees all DMA + Pt visible for B.
// ---------------------------------------------------------------------------
__launch_bounds__(256, 4)
__global__ void main_kernel(const float* __restrict__ x, const float* __restrict__ Ap,
                            const half_t* __restrict__ WH, float* __restrict__ outbuf,
                            int mode) {
    __shared__ float  Xf[TB * D_];     // 16 KB  x batch, f32, 16B-chunk XOR swizzle
    __shared__ half_t WHl[8192];       // 16 KB  weights, MFMA A-frag order
    __shared__ half_t Pt[K_ * 64];     // 8 KB   p transposed, col-block XOR swizzle

    const int tid  = threadIdx.x;
    const int lane = tid & 63;
    const int wv   = tid >> 6;
    const int chunk = blockIdx.x;
    const int n     = blockIdx.y;
    const int q     = lane >> 4;
    const int c0    = lane & 15;
    const int tok   = 16 * wv + c0;   // this lane's token within the batch
    const int sig = wv >> 1;
    const int dh  = wv & 1;

    const size_t xbase = ((size_t)n * T_ + (size_t)chunk * TOK_PER_BLOCK) * (size_t)D_;

    // ---- prologue: WH -> LDS, x batch0 -> LDS (async), Ap -> regs ----
#pragma unroll
    for (int i = 0; i < 4; ++i)
        gll16(WH + wv * 2048 + i * 512 + lane * 8,
              (char*)WHl + wv * 4096 + i * 1024);
    {
        const float* gb = x + xbase;
#pragma unroll
        for (int i = 0; i < 4; ++i) {
            const int row = 16 * wv + 4 * i + (lane >> 4);
            const int ss  = (lane & 15) ^ (row & 15);
            gll16(gb + row * 64 + ss * 4, (char*)Xf + wv * 4096 + i * 1024);
        }
    }
    v4f apf[4];
#pragma unroll
    for (int t = 0; t < 4; ++t) apf[t] = *(const v4f*)(Ap + 16 * t + 4 * q);

    float S0loc[16];
#pragma unroll
    for (int j = 0; j < 16; ++j) S0loc[j] = 0.f;

    v16f accB[2];
#pragma unroll
    for (int m = 0; m < 2; ++m)
#pragma unroll
        for (int r = 0; r < 16; ++r) accB[m][r] = 0.f;

    asm volatile("s_waitcnt vmcnt(0)" ::: "memory");
    __syncthreads();   // WHl fully staged (all waves), Xf batch0 staged

#pragma unroll 1
    for (int batch = 0; batch < NBATCH; ++batch) {
        // own-wave x DMA for this batch has landed?
        asm volatile("s_waitcnt vmcnt(0)" ::: "memory");

        // ---------------- Phase A ----------------
        v8h xh0, xh1, qh0, qh1;
        {
            const float* XfR = Xf + tok * 64;
            const int sb = (2 * q) ^ c0;           // slot of chunk 2q in row tok
            const v4f a = *(const v4f*)(XfR + 4 * sb);
            const v4f b = *(const v4f*)(XfR + 4 * (sb ^ 1));
            const v4f c = *(const v4f*)(XfR + 4 * (sb ^ 8));
            const v4f d = *(const v4f*)(XfR + 4 * (sb ^ 9));
            xh0[0] = (half_t)a[0]; xh0[1] = (half_t)a[1]; xh0[2] = (half_t)a[2]; xh0[3] = (half_t)a[3];
            xh0[4] = (half_t)b[0]; xh0[5] = (half_t)b[1]; xh0[6] = (half_t)b[2]; xh0[7] = (half_t)b[3];
            xh1[0] = (half_t)c[0]; xh1[1] = (half_t)c[1]; xh1[2] = (half_t)c[2]; xh1[3] = (half_t)c[3];
            xh1[4] = (half_t)d[0]; xh1[5] = (half_t)d[1]; xh1[6] = (half_t)d[2]; xh1[7] = (half_t)d[3];
            qh0[0] = (half_t)(a[0]*a[0]); qh0[1] = (half_t)(a[1]*a[1]);
            qh0[2] = (half_t)(a[2]*a[2]); qh0[3] = (half_t)(a[3]*a[3]);
            qh0[4] = (half_t)(b[0]*b[0]); qh0[5] = (half_t)(b[1]*b[1]);
            qh0[6] = (half_t)(b[2]*b[2]); qh0[7] = (half_t)(b[3]*b[3]);
            qh1[0] = (half_t)(c[0]*c[0]); qh1[1] = (half_t)(c[1]*c[1]);
            qh1[2] = (half_t)(c[2]*c[2]); qh1[3] = (half_t)(c[3]*c[3]);
            qh1[4] = (half_t)(d[0]*d[0]); qh1[5] = (half_t)(d[1]*d[1]);
            qh1[6] = (half_t)(d[2]*d[2]); qh1[7] = (half_t)(d[3]*d[3]);
        }
        {
            const half_t* WHp = WHl + lane * 8;
            v4f acc[4];
#pragma unroll
            for (int t = 0; t < 4; ++t) acc[t] = (v4f)(0.f);
#pragma unroll
            for (int t = 0; t < 4; ++t) {
                const v8h w0 = *(const v8h*)(WHp + (t * 4 + 0) * 512);
                const v8h w1 = *(const v8h*)(WHp + (t * 4 + 1) * 512);
                const v8h w2 = *(const v8h*)(WHp + (t * 4 + 2) * 512);
                const v8h w3 = *(const v8h*)(WHp + (t * 4 + 3) * 512);
                acc[t] = __builtin_amdgcn_mfma_f32_16x16x32_f16(w0, xh0, acc[t], 0, 0, 0);
                acc[t] = __builtin_amdgcn_mfma_f32_16x16x32_f16(w1, xh1, acc[t], 0, 0, 0);
                acc[t] = __builtin_amdgcn_mfma_f32_16x16x32_f16(w2, qh0, acc[t], 0, 0, 0);
                acc[t] = __builtin_amdgcn_mfma_f32_16x16x32_f16(w3, qh1, acc[t], 0, 0, 0);
            }
            float pv[16];
            float m = -1e30f;
#pragma unroll
            for (int t = 0; t < 4; ++t)
#pragma unroll
                for (int r = 0; r < 4; ++r) {
                    const float lg = acc[t][r] + apf[t][r];
                    pv[t * 4 + r] = lg;
                    m = fmaxf(m, lg);
                }
            m = fmaxf(m, __shfl_xor(m, 16, 64));
            m = fmaxf(m, __shfl_xor(m, 32, 64));
            float ssum = 0.f;
#pragma unroll
            for (int j = 0; j < 16; ++j) { pv[j] = __expf(pv[j] - m); ssum += pv[j]; }
            ssum += __shfl_xor(ssum, 16, 64);
            ssum += __shfl_xor(ssum, 32, 64);
            const float rs = 1.f / ssum;
#pragma unroll
            for (int j = 0; j < 16; ++j) { pv[j] *= rs; S0loc[j] += pv[j]; }
            // Pt write, col-block swizzle: block = (tok>>3) ^ (kc&7)
            const int tb3 = tok >> 3, t7 = tok & 7;
#pragma unroll
            for (int t = 0; t < 4; ++t)
#pragma unroll
                for (int r = 0; r < 4; ++r) {
                    const int kc = 16 * t + 4 * q + r;
                    Pt[kc * 64 + ((tb3 ^ (kc & 7)) << 3) + t7] = (half_t)pv[t * 4 + r];
                }
        }
        __syncthreads();   // all DMA rows + Pt visible

        // ---------------- Phase B ----------------
        {
            const int m   = lane & 31;
            const int h   = lane >> 5;
            const int cnk = 8 * dh + (m >> 2);   // f32 16B-chunk of this lane's d
            const int sub = m & 3;
#pragma unroll
            for (int st = 0; st < 4; ++st) {
                const int tB = 16 * st + 8 * h;
                const int sA = ((tB >> 3) ^ (m & 7)) << 3;
                const v8h a0 = *(const v8h*)(Pt + m * 64 + sA);
                const v8h a1 = *(const v8h*)(Pt + (m + 32) * 64 + sA);
                v8h bf;
#pragma unroll
                for (int j = 0; j < 8; ++j) {
                    const int rB = tB + j;
                    const float v = Xf[rB * 64 + ((cnk ^ (rB & 15)) << 2) + sub];
                    bf[j] = (half_t)(sig ? v * v : v);
                }
                accB[0] = __builtin_amdgcn_mfma_f32_32x32x16_f16(a0, bf, accB[0], 0, 0, 0);
                accB[1] = __builtin_amdgcn_mfma_f32_32x32x16_f16(a1, bf, accB[1], 0, 0, 0);
            }
        }
        __syncthreads();   // Xf + Pt free for next batch

        if (batch + 1 < NBATCH) {
            const float* gb = x + xbase + (size_t)(batch + 1) * (TB * D_);
#pragma unroll
            for (int i = 0; i < 4; ++i) {
                const int row = 16 * wv + 4 * i + (lane >> 4);
                const int ss  = (lane & 15) ^ (row & 15);
                gll16(gb + row * 64 + ss * 4, (char*)Xf + wv * 4096 + i * 1024);
            }
        }
    }

    // -------- flush (Pt storage reused as s0sh; all Pt reads done) --------
#pragma unroll
    for (int j = 0; j < 16; ++j) {
        float v = S0loc[j];
        v += __shfl_xor(v, 1, 64);
        v += __shfl_xor(v, 2, 64);
        v += __shfl_xor(v, 4, 64);
        v += __shfl_xor(v, 8, 64);
        S0loc[j] = v;
    }
    float (*s0sh)[64] = (float (*)[64])(void*)Pt;
    if (c0 == 0) {
#pragma unroll
        for (int t = 0; t < 4; ++t)
#pragma unroll
            for (int r = 0; r < 4; ++r)
                s0sh[wv][16 * t + 4 * q + r] = S0loc[t * 4 + r];
    }
    __syncthreads();

    if (mode == 1) {
        float* dstb = outbuf + (size_t)(n * CHUNKS + chunk) * STATS_PER_N;
        if (tid < 64)
            __builtin_nontemporal_store(
                s0sh[0][tid] + s0sh[1][tid] + s0sh[2][tid] + s0sh[3][tid], &dstb[tid]);
        const int d = 32 * dh + (lane & 31);
        float* dst = dstb + 64 + sig * 4096;
#pragma unroll
        for (int mt = 0; mt < 2; ++mt)
#pragma unroll
            for (int r = 0; r < 16; ++r) {
                const int kc = 32 * mt + (r & 3) + 8 * (r >> 2) + 4 * (lane >> 5);
                __builtin_nontemporal_store(accB[mt][r], &dst[kc * 64 + d]);
            }
    } else {
        float* sb = outbuf + (size_t)n * STATS_PER_N;
        if (tid < 64)
            atomicAdd(&sb[tid], s0sh[0][tid] + s0sh[1][tid] + s0sh[2][tid] + s0sh[3][tid]);
        const int d = 32 * dh + (lane & 31);
        float* dst = sb + 64 + sig * 4096;
#pragma unroll
        for (int mt = 0; mt < 2; ++mt)
#pragma unroll
            for (int r = 0; r < 16; ++r) {
                const int kc = 32 * mt + (r & 3) + 8 * (r >> 2) + 4 * (lane >> 5);
                atomicAdd(&dst[kc * 64 + d], accB[mt][r]);
            }
    }
}

// ---------------------------------------------------------------------------
// reduce_pow (grid (33, N)): sum partials over chunks, apply v0/v1/v2 transform
// + signed sqrt, write us in OUTPUT order; one ssq atomic per block.
// ---------------------------------------------------------------------------
__global__ void reduce_pow_kernel(const float* __restrict__ partials,
                                  const float* __restrict__ w, const float* __restrict__ mu,
                                  const float* __restrict__ cv,
                                  float* __restrict__ us, float* __restrict__ ssq) {
    __shared__ float red[4];
    const int e = blockIdx.x * 256 + threadIdx.x;
    const int n = blockIdx.y;
    float u = 0.f;
    if (e < STATS_PER_N) {
        const float* base = partials + (size_t)n * CHUNKS * STATS_PER_N;
        float sv = 0.f;
#pragma unroll 8
        for (int c = 0; c < CHUNKS; ++c) sv += base[(size_t)c * STATS_PER_N + e];
        float v; int oidx;
        if (e < 64) {
            const float wv = w[e];
            v = (sv - (float)T_ * wv) * rsqrtf(wv);
            oidx = e * 129;
        } else if (e < 64 + 4096) {
            const int idx = e - 64, k = idx >> 6, d = idx & 63;
            float s0v = 0.f;
#pragma unroll 8
            for (int c = 0; c < CHUNKS; ++c) s0v += base[(size_t)c * STATS_PER_N + k];
            v = (sv - mu[idx] * s0v) * rsqrtf(w[k] * cv[idx]);
            oidx = k * 129 + 1 + d;
        } else {
            const int idx = e - 4160, k = idx >> 6, d = idx & 63;
            float s0v = 0.f, s1v = 0.f;
#pragma unroll 4
            for (int c = 0; c < CHUNKS; ++c) {
                s0v += base[(size_t)c * STATS_PER_N + k];
                s1v += base[(size_t)c * STATS_PER_N + 64 + idx];
            }
            const float m_ = mu[idx], c_ = cv[idx];
            v = (sv - 2.f * m_ * s1v + (m_ * m_ - c_) * s0v) * (rsqrtf(2.f * w[k]) / c_);
            oidx = k * 129 + 65 + d;
        }
        u = (v >= 0.f) ? sqrtf(v) : -sqrtf(-v);
        us[(size_t)n * STATS_PER_N + oidx] = u;
    }
    float ss = u * u;
#pragma unroll
    for (int off = 32; off > 0; off >>= 1) ss += __shfl_xor(ss, off, 64);
    if ((threadIdx.x & 63) == 0) red[threadIdx.x >> 6] = ss;
    __syncthreads();
    if (threadIdx.x == 0)
        atomicAdd(&ssq[n], red[0] + red[1] + red[2] + red[3]);
}

// ---------------------------------------------------------------------------
// scale (grid (33, N)): out = us * rsqrt(ssq[n])
// ---------------------------------------------------------------------------
__global__ void scale_kernel(const float* __restrict__ us, const float* __restrict__ ssq,
                             float* __restrict__ out) {
    const int e = blockIdx.x * 256 + threadIdx.x;
    const int n = blockIdx.y;
    if (e < STATS_PER_N)
        out[(size_t)n * STATS_PER_N + e] = us[(size_t)n * STATS_PER_N + e] * rsqrtf(ssq[n]);
}

// ---------------------------------------------------------------------------
// fallback finalize (small-ws atomic path).
// ---------------------------------------------------------------------------
__global__ void fin_kernel(const float* __restrict__ w, const float* __restrict__ mu,
                           const float* __restrict__ cv, const float* __restrict__ stats,
                           float* __restrict__ out) {
    __shared__ float us[STATS_PER_N];
    __shared__ float red[4];
    const int n   = blockIdx.x;
    const int tid = threadIdx.x;
    const float* sb = stats + (size_t)n * STATS_PER_N;

    float ss = 0.f;
    if (tid < 64) {
        const float wv = w[tid];
        const float v = (sb[tid] - (float)T_ * wv) * rsqrtf(wv);
        const float u = (v >= 0.f) ? sqrtf(v) : -sqrtf(-v);
        us[tid * 129] = u;
        ss = fmaf(u, u, ss);
    }
#pragma unroll 1
    for (int i = 0; i < 16; ++i) {
        const int idx = i * 256 + tid;
        const int k = idx >> 6, d = idx & 63;
        const float v = (sb[64 + idx] - mu[idx] * sb[k]) * rsqrtf(w[k] * cv[idx]);
        const float u = (v >= 0.f) ? sqrtf(v) : -sqrtf(-v);
        us[k * 129 + 1 + d] = u;
        ss = fmaf(u, u, ss);
    }
#pragma unroll 1
    for (int i = 0; i < 16; ++i) {
        const int idx = i * 256 + tid;
        const int k = idx >> 6, d = idx & 63;
        const float m_ = mu[idx], c_ = cv[idx];
        const float s1v = sb[64 + idx], s2v = sb[64 + 4096 + idx];
        const float v = (s2v - 2.f * m_ * s1v + (m_ * m_ - c_) * sb[k]) *
                        (rsqrtf(2.f * w[k]) / c_);
        const float u = (v >= 0.f) ? sqrtf(v) : -sqrtf(-v);
        us[k * 129 + 65 + d] = u;
        ss = fmaf(u, u, ss);
    }
#pragma unroll
    for (int off = 32; off > 0; off >>= 1) ss += __shfl_xor(ss, off, 64);
    if ((tid & 63) == 0) red[tid >> 6] = ss;
    __syncthreads();
    const float tot = red[0] + red[1] + red[2] + red[3];
    const float rn = rsqrtf(tot);
    for (int e = tid; e < STATS_PER_N; e += 256)
        out[(size_t)n * STATS_PER_N + e] = us[e] * rn;
}

// ---------------------------------------------------------------------------
extern "C" void kernel_launch(void* const* d_in, const int* in_sizes, int n_in,
                              void* d_out, int out_size, void* d_ws, size_t ws_size,
                              hipStream_t stream) {
    const float* x  = (const float*)d_in[0];
    const float* w  = (const float*)d_in[1];
    const float* mu = (const float*)d_in[2];
    const float* cv = (const float*)d_in[3];
    float* out = (float*)d_out;

    const size_t part_elems = (size_t)CHUNKS * N_ * STATS_PER_N;   // 8.45M floats
    const size_t us_elems   = (size_t)N_ * STATS_PER_N;
    const size_t need_big = (part_elems + us_elems + 32 + K_ + (size_t)K_ * 64) * sizeof(float);

    if (ws_size >= need_big) {
        float* partials = (float*)d_ws;
        float* us  = partials + part_elems;
        float* ssq = us + us_elems;
        float* Ap  = ssq + 32;
        half_t* WH = (half_t*)(Ap + K_);

        prep_kernel<<<9, 256, 0, stream>>>(w, mu, cv, Ap, WH, ssq);
        main_kernel<<<dim3(CHUNKS, N_), 256, 0, stream>>>(x, Ap, WH, partials, 1);
        reduce_pow_kernel<<<dim3(33, N_), 256, 0, stream>>>(partials, w, mu, cv, us, ssq);
        scale_kernel<<<dim3(33, N_), 256, 0, stream>>>(us, ssq, out);
    } else {
        float* stats = (float*)d_ws;
        float* ssq = stats + us_elems;
        float* Ap  = ssq + 32;
        half_t* WH = (half_t*)(Ap + K_);

        hipMemsetAsync(stats, 0, us_elems * sizeof(float), stream);
        prep_kernel<<<9, 256, 0, stream>>>(w, mu, cv, Ap, WH, ssq);
        main_kernel<<<dim3(CHUNKS, N_), 256, 0, stream>>>(x, Ap, WH, stats, 0);
        fin_kernel<<<N_, 256, 0, stream>>>(w, mu, cv, stats, out);
    }
}

// Round 3
// 148.175 us; speedup vs baseline: 1.2287x; 1.2287x over previous
//
#include <hip/hip_runtime.h>
#include <math.h>

#define N_  32
#define T_  8192
#define D_  64
#define K_  64
#define CHUNKS 24                      // 768 blocks = exactly 3/CU, one round
#define TB 64                          // tokens per batch
#define BATCHES_PER_N (T_ / TB)        // 128 = 24*5 + 8 heavy
#define STATS_PER_N (K_ + 2 * K_ * D_) // 8256
#define XSTR 72                        // f16 stride for Xs/Qs/Pt rows

typedef _Float16 half_t;
typedef __attribute__((ext_vector_type(8)))  _Float16 v8h;
typedef __attribute__((ext_vector_type(4)))  float    v4f;
typedef __attribute__((ext_vector_type(16))) float    v16f;

// ---------------------------------------------------------------------------
// prep (grid 9): blocks 0..7 pack WH (f16 MFMA A-frag order);
// block 8: Ap[k] = 2 log w - 0.5*sum_d(log c + mu^2/c), and zero ssq[32].
// ---------------------------------------------------------------------------
__global__ void prep_kernel(const float* __restrict__ w, const float* __restrict__ mu,
                            const float* __restrict__ cv, float* __restrict__ Ap,
                            half_t* __restrict__ WH, float* __restrict__ ssq) {
    if (blockIdx.x < 8) {
#pragma unroll
        for (int i = 0; i < 4; ++i) {
            const int e = blockIdx.x * 1024 + i * 256 + threadIdx.x;  // 0..8191
            const int j = e & 7, l = (e >> 3) & 63, fs = e >> 9;
            const int tile = fs >> 2, s = fs & 3;
            const int kc = 16 * tile + (l & 15);
            const int f  = 32 * s + 8 * (l >> 4) + j;
            float val;
            if (f < 64) val = mu[kc * 64 + f] / cv[kc * 64 + f];
            else        val = -0.5f / cv[kc * 64 + (f - 64)];
            WH[e] = (half_t)val;
        }
    } else {
        if (threadIdx.x < 32) ssq[threadIdx.x] = 0.f;
        if (threadIdx.x < K_) {
            const int k = threadIdx.x;
            float acc = 0.f;
            for (int d = 0; d < D_; ++d) {
                const int idx = k * D_ + d;
                const float c = cv[idx], m = mu[idx];
                acc += logf(c) + m * m / c;
            }
            Ap[k] = 2.f * logf(w[k]) - 0.5f * acc;
        }
    }
}

// ---------------------------------------------------------------------------
// main: grid (24, 32) = 768 blocks, block 256 (4 waves).
// R3: identical inner structure to the best-measured kernel (W-in-registers,
// f16 Xs/Qs staging, register x-prefetch, 28.6 KB LDS, 2 barriers/batch) —
// but the grid now MATCHES the 3-blocks/CU residency that ~132 unified
// regs/wave allows: 768 blocks = one clean round (the 1024-block grid ran
// ragged 3+1 rounds, measured 20% occupancy). Chunks carry 5 or 6 batches;
// heavy chunks at (c%3)==((3-n%3)%3) -> exactly one heavy per 3 consecutive
// blocks -> every CU gets 5+5+6 = 16 batches (balanced makespan).
// ---------------------------------------------------------------------------
__launch_bounds__(256, 3)
__global__ void main_kernel(const float* __restrict__ x, const float* __restrict__ Ap,
                            const half_t* __restrict__ WH, float* __restrict__ outbuf,
                            int mode) {
    __shared__ half_t Xs[TB][XSTR];   // 9.0 KB
    __shared__ half_t Qs[TB][XSTR];   // 9.0 KB
    __shared__ half_t Pt[K_][XSTR];   // 9.0 KB (transposed p: row=kc, col=token)
    __shared__ float  s0sh[4][64];    // 1.0 KB

    const int tid  = threadIdx.x;
    const int lane = tid & 63;
    const int wv   = tid >> 6;
    const int chunk = blockIdx.x;
    const int n     = blockIdx.y;
    const int q     = lane >> 4;
    const int c0    = lane & 15;
    const int tok   = 16 * wv + c0;   // this lane's token within the batch

    // batch range for this (n, chunk): heavy chunks (6 batches) where
    // (chunk % 3) == r, others 5; off = 5*chunk + #heavies before chunk.
    const int r3   = (3 - (n % 3)) % 3;
    const int hcnt = (chunk + 2 - r3) / 3;          // heavies in [0, chunk)
    const int boff = 5 * chunk + hcnt;              // first batch index
    const int cnt  = 5 + ((chunk % 3) == r3 ? 1 : 0);

    // resident weight A-frags
    v8h Wf[16];
#pragma unroll
    for (int t = 0; t < 4; ++t)
#pragma unroll
        for (int s = 0; s < 4; ++s)
            Wf[t * 4 + s] = *(const v8h*)(WH + (size_t)((t * 4 + s) * 64 + lane) * 8);

    float apv[16];
#pragma unroll
    for (int t = 0; t < 4; ++t)
#pragma unroll
        for (int r = 0; r < 4; ++r) apv[t * 4 + r] = Ap[16 * t + 4 * q + r];

    float S0loc[16];
#pragma unroll
    for (int j = 0; j < 16; ++j) S0loc[j] = 0.f;

    const int sig = wv >> 1;
    const int dh  = wv & 1;
    v16f accB[2];
#pragma unroll
    for (int m = 0; m < 2; ++m)
#pragma unroll
        for (int r = 0; r < 16; ++r) accB[m][r] = 0.f;

    const size_t xbase = ((size_t)n * T_ + (size_t)boff * TB) * (size_t)D_;
    // Phase-A load geometry: lane reads token `tok`, d in [8q,8q+8) and [32+8q,+8)
    const float* xrow0 = x + xbase + tok * 64 + 8 * q;

    // preload batch 0
    float4 R[4];
    R[0] = *(const float4*)(xrow0);
    R[1] = *(const float4*)(xrow0 + 4);
    R[2] = *(const float4*)(xrow0 + 32);
    R[3] = *(const float4*)(xrow0 + 36);

#pragma unroll 1
    for (int batch = 0; batch < cnt; ++batch) {
        // ---- convert current R -> frags (registers), stage to LDS for Phase B ----
        v8h xh0, xh1, qh0, qh1;
        {
            const float4 a = R[0], b = R[1], c = R[2], d = R[3];
            xh0[0] = (half_t)a.x; xh0[1] = (half_t)a.y; xh0[2] = (half_t)a.z; xh0[3] = (half_t)a.w;
            xh0[4] = (half_t)b.x; xh0[5] = (half_t)b.y; xh0[6] = (half_t)b.z; xh0[7] = (half_t)b.w;
            xh1[0] = (half_t)c.x; xh1[1] = (half_t)c.y; xh1[2] = (half_t)c.z; xh1[3] = (half_t)c.w;
            xh1[4] = (half_t)d.x; xh1[5] = (half_t)d.y; xh1[6] = (half_t)d.z; xh1[7] = (half_t)d.w;
            qh0[0] = (half_t)(a.x * a.x); qh0[1] = (half_t)(a.y * a.y);
            qh0[2] = (half_t)(a.z * a.z); qh0[3] = (half_t)(a.w * a.w);
            qh0[4] = (half_t)(b.x * b.x); qh0[5] = (half_t)(b.y * b.y);
            qh0[6] = (half_t)(b.z * b.z); qh0[7] = (half_t)(b.w * b.w);
            qh1[0] = (half_t)(c.x * c.x); qh1[1] = (half_t)(c.y * c.y);
            qh1[2] = (half_t)(c.z * c.z); qh1[3] = (half_t)(c.w * c.w);
            qh1[4] = (half_t)(d.x * d.x); qh1[5] = (half_t)(d.y * d.y);
            qh1[6] = (half_t)(d.z * d.z); qh1[7] = (half_t)(d.w * d.w);
            *(v8h*)&Xs[tok][8 * q]      = xh0;
            *(v8h*)&Xs[tok][32 + 8 * q] = xh1;
            *(v8h*)&Qs[tok][8 * q]      = qh0;
            *(v8h*)&Qs[tok][32 + 8 * q] = qh1;
        }

        // ---- prefetch next batch (latency hidden under A-MFMA + softmax + B) ----
        if (batch + 1 < cnt) {
            const float* xr = xrow0 + (size_t)(batch + 1) * TB * D_;
            R[0] = *(const float4*)(xr);
            R[1] = *(const float4*)(xr + 4);
            R[2] = *(const float4*)(xr + 32);
            R[3] = *(const float4*)(xr + 36);
        }

        // ---------------- Phase A (register frags only) ----------------
        {
            v4f acc[4];
#pragma unroll
            for (int t = 0; t < 4; ++t) acc[t] = (v4f)(0.f);
#pragma unroll
            for (int t = 0; t < 4; ++t) {
                acc[t] = __builtin_amdgcn_mfma_f32_16x16x32_f16(Wf[t * 4 + 0], xh0, acc[t], 0, 0, 0);
                acc[t] = __builtin_amdgcn_mfma_f32_16x16x32_f16(Wf[t * 4 + 1], xh1, acc[t], 0, 0, 0);
                acc[t] = __builtin_amdgcn_mfma_f32_16x16x32_f16(Wf[t * 4 + 2], qh0, acc[t], 0, 0, 0);
                acc[t] = __builtin_amdgcn_mfma_f32_16x16x32_f16(Wf[t * 4 + 3], qh1, acc[t], 0, 0, 0);
            }
            float pv[16];
            float m = -1e30f;
#pragma unroll
            for (int t = 0; t < 4; ++t)
#pragma unroll
                for (int r = 0; r < 4; ++r) {
                    const float lg = acc[t][r] + apv[t * 4 + r];
                    pv[t * 4 + r] = lg;
                    m = fmaxf(m, lg);
                }
            m = fmaxf(m, __shfl_xor(m, 16, 64));
            m = fmaxf(m, __shfl_xor(m, 32, 64));
            float ssum = 0.f;
#pragma unroll
            for (int j = 0; j < 16; ++j) { pv[j] = __expf(pv[j] - m); ssum += pv[j]; }
            ssum += __shfl_xor(ssum, 16, 64);
            ssum += __shfl_xor(ssum, 32, 64);
            const float rs = 1.f / ssum;
#pragma unroll
            for (int j = 0; j < 16; ++j) { pv[j] *= rs; S0loc[j] += pv[j]; }
#pragma unroll
            for (int t = 0; t < 4; ++t)
#pragma unroll
                for (int r = 0; r < 4; ++r)
                    Pt[16 * t + 4 * q + r][tok] = (half_t)pv[t * 4 + r];
        }
        __syncthreads();   // Xs/Qs/Pt all visible

        // ---------------- Phase B ----------------
        {
            const half_t* Bsrc = (sig == 0) ? &Xs[0][0] : &Qs[0][0];
            const int m   = lane & 31;
            const int h   = lane >> 5;
            const int d   = 32 * dh + m;
            const half_t* Arow0 = &Pt[m][0];
            const half_t* Arow1 = &Pt[32 + m][0];
#pragma unroll
            for (int st = 0; st < 4; ++st) {
                const int tB = 16 * st + 8 * h;
                const v8h a0 = *(const v8h*)(Arow0 + tB);
                const v8h a1 = *(const v8h*)(Arow1 + tB);
                v8h bf;
#pragma unroll
                for (int j = 0; j < 8; ++j)
                    bf[j] = Bsrc[(tB + j) * XSTR + d];
                accB[0] = __builtin_amdgcn_mfma_f32_32x32x16_f16(a0, bf, accB[0], 0, 0, 0);
                accB[1] = __builtin_amdgcn_mfma_f32_32x32x16_f16(a1, bf, accB[1], 0, 0, 0);
            }
        }
        __syncthreads();   // Phase B done -> LDS reusable next batch
    }

    // -------- flush --------
#pragma unroll
    for (int j = 0; j < 16; ++j) {
        float v = S0loc[j];
        v += __shfl_xor(v, 1, 64);
        v += __shfl_xor(v, 2, 64);
        v += __shfl_xor(v, 4, 64);
        v += __shfl_xor(v, 8, 64);
        S0loc[j] = v;
    }
    if (c0 == 0) {
#pragma unroll
        for (int t = 0; t < 4; ++t)
#pragma unroll
            for (int r = 0; r < 4; ++r)
                s0sh[wv][16 * t + 4 * q + r] = S0loc[t * 4 + r];
    }
    __syncthreads();

    if (mode == 1) {
        float* dstb = outbuf + (size_t)(n * CHUNKS + chunk) * STATS_PER_N;
        if (tid < 64)
            dstb[tid] = s0sh[0][tid] + s0sh[1][tid] + s0sh[2][tid] + s0sh[3][tid];
        const int d = 32 * dh + (lane & 31);
        float* dst = dstb + 64 + sig * 4096;
#pragma unroll
        for (int mt = 0; mt < 2; ++mt)
#pragma unroll
            for (int r = 0; r < 16; ++r) {
                const int kc = 32 * mt + (r & 3) + 8 * (r >> 2) + 4 * (lane >> 5);
                dst[kc * 64 + d] = accB[mt][r];
            }
    } else {
        float* sb = outbuf + (size_t)n * STATS_PER_N;
        if (tid < 64)
            atomicAdd(&sb[tid], s0sh[0][tid] + s0sh[1][tid] + s0sh[2][tid] + s0sh[3][tid]);
        const int d = 32 * dh + (lane & 31);
        float* dst = sb + 64 + sig * 4096;
#pragma unroll
        for (int mt = 0; mt < 2; ++mt)
#pragma unroll
            for (int r = 0; r < 16; ++r) {
                const int kc = 32 * mt + (r & 3) + 8 * (r >> 2) + 4 * (lane >> 5);
                atomicAdd(&dst[kc * 64 + d], accB[mt][r]);
            }
    }
}

// ---------------------------------------------------------------------------
// reduce_pow (grid (33, N)): sum partials over 24 chunks, apply v0/v1/v2
// transform + signed sqrt, write us in OUTPUT order; one ssq atomic per block.
// ---------------------------------------------------------------------------
__global__ void reduce_pow_kernel(const float* __restrict__ partials,
                                  const float* __restrict__ w, const float* __restrict__ mu,
                                  const float* __restrict__ cv,
                                  float* __restrict__ us, float* __restrict__ ssq) {
    __shared__ float red[4];
    const int e = blockIdx.x * 256 + threadIdx.x;
    const int n = blockIdx.y;
    float u = 0.f;
    if (e < STATS_PER_N) {
        const float* base = partials + (size_t)n * CHUNKS * STATS_PER_N;
        float sv = 0.f;
#pragma unroll 8
        for (int c = 0; c < CHUNKS; ++c) sv += base[(size_t)c * STATS_PER_N + e];
        float v; int oidx;
        if (e < 64) {
            const float wv = w[e];
            v = (sv - (float)T_ * wv) * rsqrtf(wv);
            oidx = e * 129;
        } else if (e < 64 + 4096) {
            const int idx = e - 64, k = idx >> 6, d = idx & 63;
            float s0v = 0.f;
#pragma unroll 8
            for (int c = 0; c < CHUNKS; ++c) s0v += base[(size_t)c * STATS_PER_N + k];
            v = (sv - mu[idx] * s0v) * rsqrtf(w[k] * cv[idx]);
            oidx = k * 129 + 1 + d;
        } else {
            const int idx = e - 4160, k = idx >> 6, d = idx & 63;
            float s0v = 0.f, s1v = 0.f;
#pragma unroll 4
            for (int c = 0; c < CHUNKS; ++c) {
                s0v += base[(size_t)c * STATS_PER_N + k];
                s1v += base[(size_t)c * STATS_PER_N + 64 + idx];
            }
            const float m_ = mu[idx], c_ = cv[idx];
            v = (sv - 2.f * m_ * s1v + (m_ * m_ - c_) * s0v) * (rsqrtf(2.f * w[k]) / c_);
            oidx = k * 129 + 65 + d;
        }
        u = (v >= 0.f) ? sqrtf(v) : -sqrtf(-v);
        us[(size_t)n * STATS_PER_N + oidx] = u;
    }
    float ss = u * u;
#pragma unroll
    for (int off = 32; off > 0; off >>= 1) ss += __shfl_xor(ss, off, 64);
    if ((threadIdx.x & 63) == 0) red[threadIdx.x >> 6] = ss;
    __syncthreads();
    if (threadIdx.x == 0)
        atomicAdd(&ssq[n], red[0] + red[1] + red[2] + red[3]);
}

// ---------------------------------------------------------------------------
// scale (grid (33, N)): out = us * rsqrt(ssq[n])
// ---------------------------------------------------------------------------
__global__ void scale_kernel(const float* __restrict__ us, const float* __restrict__ ssq,
                             float* __restrict__ out) {
    const int e = blockIdx.x * 256 + threadIdx.x;
    const int n = blockIdx.y;
    if (e < STATS_PER_N)
        out[(size_t)n * STATS_PER_N + e] = us[(size_t)n * STATS_PER_N + e] * rsqrtf(ssq[n]);
}

// ---------------------------------------------------------------------------
// fallback finalize (small-ws atomic path).
// ---------------------------------------------------------------------------
__global__ void fin_kernel(const float* __restrict__ w, const float* __restrict__ mu,
                           const float* __restrict__ cv, const float* __restrict__ stats,
                           float* __restrict__ out) {
    __shared__ float us[STATS_PER_N];
    __shared__ float red[4];
    const int n   = blockIdx.x;
    const int tid = threadIdx.x;
    const float* sb = stats + (size_t)n * STATS_PER_N;

    float ss = 0.f;
    if (tid < 64) {
        const float wv = w[tid];
        const float v = (sb[tid] - (float)T_ * wv) * rsqrtf(wv);
        const float u = (v >= 0.f) ? sqrtf(v) : -sqrtf(-v);
        us[tid * 129] = u;
        ss = fmaf(u, u, ss);
    }
#pragma unroll 1
    for (int i = 0; i < 16; ++i) {
        const int idx = i * 256 + tid;
        const int k = idx >> 6, d = idx & 63;
        const float v = (sb[64 + idx] - mu[idx] * sb[k]) * rsqrtf(w[k] * cv[idx]);
        const float u = (v >= 0.f) ? sqrtf(v) : -sqrtf(-v);
        us[k * 129 + 1 + d] = u;
        ss = fmaf(u, u, ss);
    }
#pragma unroll 1
    for (int i = 0; i < 16; ++i) {
        const int idx = i * 256 + tid;
        const int k = idx >> 6, d = idx & 63;
        const float m_ = mu[idx], c_ = cv[idx];
        const float s1v = sb[64 + idx], s2v = sb[64 + 4096 + idx];
        const float v = (s2v - 2.f * m_ * s1v + (m_ * m_ - c_) * sb[k]) *
                        (rsqrtf(2.f * w[k]) / c_);
        const float u = (v >= 0.f) ? sqrtf(v) : -sqrtf(-v);
        us[k * 129 + 65 + d] = u;
        ss = fmaf(u, u, ss);
    }
#pragma unroll
    for (int off = 32; off > 0; off >>= 1) ss += __shfl_xor(ss, off, 64);
    if ((tid & 63) == 0) red[tid >> 6] = ss;
    __syncthreads();
    const float tot = red[0] + red[1] + red[2] + red[3];
    const float rn = rsqrtf(tot);
    for (int e = tid; e < STATS_PER_N; e += 256)
        out[(size_t)n * STATS_PER_N + e] = us[e] * rn;
}

// ---------------------------------------------------------------------------
extern "C" void kernel_launch(void* const* d_in, const int* in_sizes, int n_in,
                              void* d_out, int out_size, void* d_ws, size_t ws_size,
                              hipStream_t stream) {
    const float* x  = (const float*)d_in[0];
    const float* w  = (const float*)d_in[1];
    const float* mu = (const float*)d_in[2];
    const float* cv = (const float*)d_in[3];
    float* out = (float*)d_out;

    const size_t part_elems = (size_t)CHUNKS * N_ * STATS_PER_N;   // 6.34M floats
    const size_t us_elems   = (size_t)N_ * STATS_PER_N;
    const size_t need_big = (part_elems + us_elems + 32 + K_ + (size_t)K_ * 64) * sizeof(float);

    if (ws_size >= need_big) {
        float* partials = (float*)d_ws;
        float* us  = partials + part_elems;
        float* ssq = us + us_elems;
        float* Ap  = ssq + 32;
        half_t* WH = (half_t*)(Ap + K_);

        prep_kernel<<<9, 256, 0, stream>>>(w, mu, cv, Ap, WH, ssq);
        main_kernel<<<dim3(CHUNKS, N_), 256, 0, stream>>>(x, Ap, WH, partials, 1);
        reduce_pow_kernel<<<dim3(33, N_), 256, 0, stream>>>(partials, w, mu, cv, us, ssq);
        scale_kernel<<<dim3(33, N_), 256, 0, stream>>>(us, ssq, out);
    } else {
        float* stats = (float*)d_ws;
        float* ssq = stats + us_elems;
        float* Ap  = ssq + 32;
        half_t* WH = (half_t*)(Ap + K_);

        hipMemsetAsync(stats, 0, us_elems * sizeof(float), stream);
        prep_kernel<<<9, 256, 0, stream>>>(w, mu, cv, Ap, WH, ssq);
        main_kernel<<<dim3(CHUNKS, N_), 256, 0, stream>>>(x, Ap, WH, stats, 0);
        fin_kernel<<<N_, 256, 0, stream>>>(w, mu, cv, stats, out);
    }
}